// Round 17
// baseline (74.956 us; speedup 1.0000x reference)
//
#include <hip/hip_runtime.h>

// SparseSelfAttention, algebraically reduced:
//   out[hd] = sum_g c_g * softmax(Q_hd K_g^T / 16) @ Vs[(2hd-g)%4]
//   Vs[head][j] = sum_{w=-2..2} v[head][(j+2w)%N]
//   c_g = 2 if (hd-g)%4==2 else 1
// N=2304 tokens, 4 heads, dh=64.
//
// R17: LDS-PIPE halving. Model: per tile LDS moved 48KB (16 stage + 32 read)
// -> ds pipe ~22us of k_flash's 35. V leaves LDS: K stays LDS-staged (shared
// by 4 waves, counted vmcnt), V goes global->REGISTER ping-pong ONE TILE
// AHEAD (R4-proven pattern; R11's regression issued V mid-body with naked
// latency). LDS/block 32->16KB; LDS bytes/tile halve. Manual 2-tile unroll
// keeps V banks as named registers (rule #20).
// R16: no unions/pointer-to-local. R12: no split-K x8. R6: VGPR<128 target.

#define N_TOK 2304
#define OUTC 256
#define HSZ (N_TOK * 64)   // halfs per head = 147456

typedef _Float16 half8 __attribute__((ext_vector_type(8)));
typedef _Float16 half4 __attribute__((ext_vector_type(4)));
typedef float f32x4 __attribute__((ext_vector_type(4)));

typedef __attribute__((address_space(3))) unsigned int as3_u32;
typedef __attribute__((address_space(1))) unsigned int as1_u32;

__device__ __forceinline__ f32x4 mfma16(half8 a, half8 b, f32x4 c) {
  return __builtin_amdgcn_mfma_f32_16x16x32_f16(a, b, c, 0, 0, 0);
}

__device__ __forceinline__ void gload_lds16(const _Float16* g, _Float16* l) {
  __builtin_amdgcn_global_load_lds((const as1_u32*)g, (as3_u32*)l, 16, 0, 0);
}

// by-value f32x8 -> f16x8 convert; compiler fuses cast pairs to v_cvt_pk (m240)
__device__ __forceinline__ half8 cvt8(float4 a, float4 b) {
  half8 h;
  h[0] = (_Float16)a.x; h[1] = (_Float16)a.y; h[2] = (_Float16)a.z; h[3] = (_Float16)a.w;
  h[4] = (_Float16)b.x; h[5] = (_Float16)b.y; h[6] = (_Float16)b.z; h[7] = (_Float16)b.w;
  return h;
}

// ---- kernel 1: QKV projection (f32 in, LDS-staged coalesced epilogues) ----
// mat 0 -> Qh[hd][n][d] row-major, scaled log2(e)/16
// mat 1 -> KF fragment-major: block (bx,hd) owns KF[hd*HSZ + bx*4096 ..+4096)
// mat 2 -> VF fragment-major SMOOTHED: A-operand is xs (5-shift sum of x),
//          bias 5*bv; block (bx,vh) owns VF[vh*HSZ + bx*4096 ..+4096)
__global__ __launch_bounds__(256) void k_proj(
    const float* __restrict__ x, const float* __restrict__ Wq,
    const float* __restrict__ Wk, const float* __restrict__ Wv,
    const float* __restrict__ bq, const float* __restrict__ bk,
    const float* __restrict__ bv,
    _Float16* __restrict__ Qh, _Float16* __restrict__ KF, _Float16* __restrict__ VF) {
  __shared__ _Float16 stg[4096];
  const int w = threadIdx.x >> 6, lane = threadIdx.x & 63;
  const int lr = lane & 15, lk = lane >> 4;
  const int n0 = blockIdx.x * 64 + w * 16;
  const int o0 = blockIdx.y * 64;
  const int mat = blockIdx.z;
  const float* W = (mat == 0) ? Wq : (mat == 1) ? Wk : Wv;
  f32x4 acc[4] = {};

  if (mat == 2) {
    const float* rp0; const float* rp1; const float* rp2;
    const float* rp3; const float* rp4;
    {
      int r0 = (n0 + lr - 4 + N_TOK) % N_TOK;
      int r1 = (n0 + lr - 2 + N_TOK) % N_TOK;
      int r2 = (n0 + lr) % N_TOK;
      int r3 = (n0 + lr + 2) % N_TOK;
      int r4 = (n0 + lr + 4) % N_TOK;
      rp0 = x + (size_t)r0 * OUTC + 8 * lk;
      rp1 = x + (size_t)r1 * OUTC + 8 * lk;
      rp2 = x + (size_t)r2 * OUTC + 8 * lk;
      rp3 = x + (size_t)r3 * OUTC + 8 * lk;
      rp4 = x + (size_t)r4 * OUTC + 8 * lk;
    }
#pragma unroll
    for (int kk = 0; kk < 8; ++kk) {
      float4 s0 = *(const float4*)(rp0 + 32 * kk);
      float4 s1 = *(const float4*)(rp1 + 32 * kk);
      float4 s2 = *(const float4*)(rp2 + 32 * kk);
      float4 s3 = *(const float4*)(rp3 + 32 * kk);
      float4 s4 = *(const float4*)(rp4 + 32 * kk);
      float4 t0 = *(const float4*)(rp0 + 32 * kk + 4);
      float4 t1 = *(const float4*)(rp1 + 32 * kk + 4);
      float4 t2 = *(const float4*)(rp2 + 32 * kk + 4);
      float4 t3 = *(const float4*)(rp3 + 32 * kk + 4);
      float4 t4 = *(const float4*)(rp4 + 32 * kk + 4);
      float4 lo, hi;
      lo.x = s0.x + s1.x + s2.x + s3.x + s4.x;
      lo.y = s0.y + s1.y + s2.y + s3.y + s4.y;
      lo.z = s0.z + s1.z + s2.z + s3.z + s4.z;
      lo.w = s0.w + s1.w + s2.w + s3.w + s4.w;
      hi.x = t0.x + t1.x + t2.x + t3.x + t4.x;
      hi.y = t0.y + t1.y + t2.y + t3.y + t4.y;
      hi.z = t0.z + t1.z + t2.z + t3.z + t4.z;
      hi.w = t0.w + t1.w + t2.w + t3.w + t4.w;
      half8 a = cvt8(lo, hi);
#pragma unroll
      for (int c = 0; c < 4; ++c) {
        const float* wrow = W + (size_t)(o0 + 16*c + lr) * OUTC + 32*kk + 8*lk;
        half8 b = cvt8(*(const float4*)(wrow), *(const float4*)(wrow + 4));
        acc[c] = mfma16(a, b, acc[c]);
      }
    }
    // stage fragment-major + k-slot-permuted:
    //   f = c*128 + (w>>1)*64 + lk*16 + lr,  i = 4*(w&1) + r
#pragma unroll
    for (int c = 0; c < 4; ++c) {
      float bo = 5.0f * bv[o0 + 16*c + lr];
#pragma unroll
      for (int r = 0; r < 4; ++r)
        stg[(c*128 + (w>>1)*64 + lk*16 + lr)*8 + 4*(w&1) + r] =
            (_Float16)(acc[c][r] + bo);
    }
    __syncthreads();
    _Float16* dst = VF + (size_t)blockIdx.y * HSZ + (size_t)blockIdx.x * 4096;
    ((half8*)dst)[threadIdx.x]       = ((const half8*)stg)[threadIdx.x];
    ((half8*)dst)[256 + threadIdx.x] = ((const half8*)stg)[256 + threadIdx.x];
    return;
  }

  const float* xrow = x + (size_t)(n0 + lr) * OUTC + 8 * lk;
#pragma unroll
  for (int kk = 0; kk < 8; ++kk) {
    half8 a = cvt8(*(const float4*)(xrow + 32 * kk),
                   *(const float4*)(xrow + 32 * kk + 4));
#pragma unroll
    for (int c = 0; c < 4; ++c) {
      const float* wrow = W + (size_t)(o0 + 16*c + lr) * OUTC + 32*kk + 8*lk;
      half8 b = cvt8(*(const float4*)(wrow), *(const float4*)(wrow + 4));
      acc[c] = mfma16(a, b, acc[c]);
    }
  }
  const float* bias = (mat == 0) ? bq : bk;
  const int hd = blockIdx.y;

  if (mat == 0) {
    const float qs = 0.0625f * 1.4426950408889634f;   // (1/16) * log2(e)
#pragma unroll
    for (int c = 0; c < 4; ++c) {
      float bo = bias[o0 + 16*c + lr];
      int d = 16*c + lr;
#pragma unroll
      for (int r = 0; r < 4; ++r)
        stg[(w*16 + 4*lk + r) * 64 + d] = (_Float16)((acc[c][r] + bo) * qs);
    }
    __syncthreads();
    _Float16* dst = Qh + ((size_t)hd * N_TOK + blockIdx.x * 64) * 64;
    ((half8*)dst)[threadIdx.x]       = ((const half8*)stg)[threadIdx.x];
    ((half8*)dst)[256 + threadIdx.x] = ((const half8*)stg)[256 + threadIdx.x];
  } else {
    // KF local idx = (w*2+h)*512 + (g4K*16 + 4*lk + r)*8 + iiK  (cK == w)
#pragma unroll
    for (int c = 0; c < 4; ++c) {
      float bo = bias[o0 + 16*c + lr];
      int d = 16*c + lr;
      int h = d >> 5, g4K = (d >> 3) & 3, iiK = d & 7;
#pragma unroll
      for (int r = 0; r < 4; ++r)
        stg[(w*2 + h)*512 + (g4K*16 + 4*lk + r)*8 + iiK] = (_Float16)(acc[c][r] + bo);
    }
    __syncthreads();
    _Float16* dst = KF + (size_t)hd * HSZ + (size_t)blockIdx.x * 4096;
    ((half8*)dst)[threadIdx.x]       = ((const half8*)stg)[threadIdx.x];
    ((half8*)dst)[256 + threadIdx.x] = ((const half8*)stg)[256 + threadIdx.x];
  }
}

// ---- kernel 2: flash attention -- K in LDS (counted vmcnt), V in register
// ping-pong one tile ahead, 2 query-strips/wave, split-K x4 ----
__global__ __launch_bounds__(256) void k_flash(
    const _Float16* __restrict__ Qh, const _Float16* __restrict__ KF,
    const _Float16* __restrict__ VF,
    _Float16* __restrict__ Opart, float* __restrict__ Lpart) {
  __shared__ __align__(16) _Float16 ldsK[2][4096];   // 8 KB per buffer
  const int wv = threadIdx.x >> 6, lane = threadIdx.x & 63;
  const int lr = lane & 15, g4 = lane >> 4;
  const int strip = blockIdx.x * 4 + wv;      // 0..71, 32 queries each
  const int n0 = strip * 32;
  const int pair = blockIdx.y;                // hd*4 + gk
  const int hd = pair >> 2, gk = pair & 3;
  const int chunk = blockIdx.z;               // 9 tiles each
  const int vh = (2*hd + 4 - gk) & 3;

  const _Float16* Qp = Qh + ((size_t)hd * N_TOK + n0 + lr) * 64 + 8*g4;
  const half8 qa0 = *(const half8*)(Qp);
  const half8 qa1 = *(const half8*)(Qp + 32);
  const half8 qb0 = *(const half8*)(Qp + 16*64);
  const half8 qb1 = *(const half8*)(Qp + 16*64 + 32);

  // K staged to LDS: each wave stages one 2KB quarter of the 8KB K tile
  const _Float16* Ksrc = KF + (size_t)gk * HSZ + (size_t)chunk * 9 * 4096
                         + wv * 1024 + lane * 8;
  // V read direct from global (fragment-major, coalesced), reg ping-pong
  const _Float16* Vsrc = VF + (size_t)vh * HSZ + (size_t)chunk * 9 * 4096 + lane * 8;

  f32x4 accA[4] = {}, accB[4] = {};
  f32x4 acclA = {}, acclB = {};
  half8 ones;
#pragma unroll
  for (int i = 0; i < 8; ++i) ones[i] = (_Float16)1.0f;

  auto stageK = [&](int t, int b) {
    const _Float16* s = Ksrc + (size_t)t * 4096;
    _Float16* d = &ldsK[b][wv * 1024];
    gload_lds16(s, d);
    gload_lds16(s + 512, d + 512);
  };

  auto body = [&](const _Float16* ldsKbase,
                  half8 v0, half8 v1, half8 v2, half8 v3,
                  half8 v4, half8 v5, half8 v6, half8 v7) {
    const _Float16* ldsKb = ldsKbase + lane * 8;
    f32x4 sA[4], sB[4];
    __builtin_amdgcn_s_setprio(1);
#pragma unroll
    for (int c = 0; c < 4; ++c) {
      half8 k0 = *(const half8*)(ldsKb + c*1024);
      half8 k1 = *(const half8*)(ldsKb + c*1024 + 512);
      f32x4 tA = {}; tA = mfma16(k0, qa0, tA); tA = mfma16(k1, qa1, tA); sA[c] = tA;
      f32x4 tB = {}; tB = mfma16(k0, qb0, tB); tB = mfma16(k1, qb1, tB); sB[c] = tB;
    }
    __builtin_amdgcn_s_setprio(0);
    // exp2 + pack: named vectors, constant indices only (no unions/pointers)
    half8 pa0, pa1, pb0, pb1;
#pragma unroll
    for (int c = 0; c < 4; ++c) {
      float eA0 = __builtin_amdgcn_exp2f(sA[c][0]);
      float eA1 = __builtin_amdgcn_exp2f(sA[c][1]);
      float eA2 = __builtin_amdgcn_exp2f(sA[c][2]);
      float eA3 = __builtin_amdgcn_exp2f(sA[c][3]);
      float eB0 = __builtin_amdgcn_exp2f(sB[c][0]);
      float eB1 = __builtin_amdgcn_exp2f(sB[c][1]);
      float eB2 = __builtin_amdgcn_exp2f(sB[c][2]);
      float eB3 = __builtin_amdgcn_exp2f(sB[c][3]);
      if (c == 0) {
        pa0[0]=(_Float16)eA0; pa0[1]=(_Float16)eA1; pa0[2]=(_Float16)eA2; pa0[3]=(_Float16)eA3;
        pb0[0]=(_Float16)eB0; pb0[1]=(_Float16)eB1; pb0[2]=(_Float16)eB2; pb0[3]=(_Float16)eB3;
      } else if (c == 1) {
        pa0[4]=(_Float16)eA0; pa0[5]=(_Float16)eA1; pa0[6]=(_Float16)eA2; pa0[7]=(_Float16)eA3;
        pb0[4]=(_Float16)eB0; pb0[5]=(_Float16)eB1; pb0[6]=(_Float16)eB2; pb0[7]=(_Float16)eB3;
      } else if (c == 2) {
        pa1[0]=(_Float16)eA0; pa1[1]=(_Float16)eA1; pa1[2]=(_Float16)eA2; pa1[3]=(_Float16)eA3;
        pb1[0]=(_Float16)eB0; pb1[1]=(_Float16)eB1; pb1[2]=(_Float16)eB2; pb1[3]=(_Float16)eB3;
      } else {
        pa1[4]=(_Float16)eA0; pa1[5]=(_Float16)eA1; pa1[6]=(_Float16)eA2; pa1[7]=(_Float16)eA3;
        pb1[4]=(_Float16)eB0; pb1[5]=(_Float16)eB1; pb1[6]=(_Float16)eB2; pb1[7]=(_Float16)eB3;
      }
    }
    __builtin_amdgcn_s_setprio(1);
    accA[0] = mfma16(v0, pa0, accA[0]); accA[0] = mfma16(v1, pa1, accA[0]);
    accB[0] = mfma16(v0, pb0, accB[0]); accB[0] = mfma16(v1, pb1, accB[0]);
    accA[1] = mfma16(v2, pa0, accA[1]); accA[1] = mfma16(v3, pa1, accA[1]);
    accB[1] = mfma16(v2, pb0, accB[1]); accB[1] = mfma16(v3, pb1, accB[1]);
    accA[2] = mfma16(v4, pa0, accA[2]); accA[2] = mfma16(v5, pa1, accA[2]);
    accB[2] = mfma16(v4, pb0, accB[2]); accB[2] = mfma16(v5, pb1, accB[2]);
    accA[3] = mfma16(v6, pa0, accA[3]); accA[3] = mfma16(v7, pa1, accA[3]);
    accB[3] = mfma16(v6, pb0, accB[3]); accB[3] = mfma16(v7, pb1, accB[3]);
    acclA = mfma16(ones, pa0, acclA); acclA = mfma16(ones, pa1, acclA);
    acclB = mfma16(ones, pb0, acclB); acclB = mfma16(ones, pb1, acclB);
    __builtin_amdgcn_s_setprio(0);
  };

#define LOADV(B, t) do { const _Float16* vp_ = Vsrc + (size_t)(t) * 4096; \
    B##0 = *(const half8*)(vp_);        B##1 = *(const half8*)(vp_ + 512); \
    B##2 = *(const half8*)(vp_ + 1024); B##3 = *(const half8*)(vp_ + 1536); \
    B##4 = *(const half8*)(vp_ + 2048); B##5 = *(const half8*)(vp_ + 2560); \
    B##6 = *(const half8*)(vp_ + 3072); B##7 = *(const half8*)(vp_ + 3584); } while (0)

  half8 vA0, vA1, vA2, vA3, vA4, vA5, vA6, vA7;
  half8 vB0, vB1, vB2, vB3, vB4, vB5, vB6, vB7;

  stageK(0, 0);
  LOADV(vA, 0);
#pragma unroll 1
  for (int u = 0; u < 4; ++u) {
    const int t = 2 * u;
    // ---- tile t (buf 0, bank A); prefetch t+1 (buf 1, bank B) ----
    stageK(t + 1, 1);
    LOADV(vB, t + 1);
    asm volatile("s_waitcnt vmcnt(10)" ::: "memory");  // own stage(t)+V(t) landed
    __builtin_amdgcn_sched_barrier(0);
    __builtin_amdgcn_s_barrier();
    __builtin_amdgcn_sched_barrier(0);
    body(&ldsK[0][0], vA0, vA1, vA2, vA3, vA4, vA5, vA6, vA7);
    __builtin_amdgcn_sched_barrier(0);
    __builtin_amdgcn_s_barrier();
    // ---- tile t+1 (buf 1, bank B); prefetch t+2 (buf 0, bank A) ----
    stageK(t + 2, 0);
    LOADV(vA, t + 2);
    asm volatile("s_waitcnt vmcnt(10)" ::: "memory");
    __builtin_amdgcn_sched_barrier(0);
    __builtin_amdgcn_s_barrier();
    __builtin_amdgcn_sched_barrier(0);
    body(&ldsK[1][0], vB0, vB1, vB2, vB3, vB4, vB5, vB6, vB7);
    __builtin_amdgcn_sched_barrier(0);
    __builtin_amdgcn_s_barrier();
  }
  // ---- tile 8 (buf 0, bank A) ----
  asm volatile("s_waitcnt vmcnt(0)" ::: "memory");
  __builtin_amdgcn_sched_barrier(0);
  __builtin_amdgcn_s_barrier();
  body(&ldsK[0][0], vA0, vA1, vA2, vA3, vA4, vA5, vA6, vA7);
#undef LOADV

  // epilogue: accl[0] is the full per-query denom (identical across r and g4)
  float invA = 1.0f / acclA[0];
  float invB = 1.0f / acclB[0];
  _Float16* Oa = Opart + (((size_t)chunk * 16 + pair) * N_TOK + n0 + lr) * 64;
  _Float16* Ob = Oa + 16 * 64;
#pragma unroll
  for (int cc = 0; cc < 4; ++cc) {
    half4 ha, hb;
#pragma unroll
    for (int r = 0; r < 4; ++r) {
      ha[r] = (_Float16)(accA[cc][r] * invA);
      hb[r] = (_Float16)(accB[cc][r] * invB);
    }
    *(half4*)(Oa + 16*cc + 4*g4) = ha;
    *(half4*)(Ob + 16*cc + 4*g4) = hb;
  }
  if (g4 == 0) {
    Lpart[((size_t)chunk * 16 + pair) * N_TOK + n0 + lr] = acclA[0];
    Lpart[((size_t)chunk * 16 + pair) * N_TOK + n0 + 16 + lr] = acclB[0];
  }
}

// ---- kernel 3: merge split-K chunks (l-weighted), weight by c_g, sum over gk ----
__global__ __launch_bounds__(256) void k_combine(
    const _Float16* __restrict__ Opart, const float* __restrict__ Lpart,
    float* __restrict__ out) {
  int gid = blockIdx.x * 256 + threadIdx.x;   // 73728 total
  int hd = gid / (N_TOK * 8);
  int rem = gid % (N_TOK * 8);
  int n = rem >> 3, db = (rem & 7) * 8;
  float acc[8] = {};
#pragma unroll
  for (int gk = 0; gk < 4; ++gk) {
    float cg = (((hd - gk) & 3) == 2) ? 2.0f : 1.0f;
    int pair = hd * 4 + gk;
    float la[4], lsum = 0.f;
#pragma unroll
    for (int ch = 0; ch < 4; ++ch) {
      la[ch] = Lpart[((size_t)ch * 16 + pair) * N_TOK + n];
      lsum += la[ch];
    }
    float rs = cg / lsum;
#pragma unroll
    for (int ch = 0; ch < 4; ++ch) {
      half8 v = *(const half8*)(Opart + (((size_t)ch * 16 + pair) * N_TOK + n) * 64 + db);
      float w = la[ch] * rs;
#pragma unroll
      for (int i = 0; i < 8; ++i) acc[i] += w * (float)v[i];
    }
  }
  float* dst = out + (size_t)n * OUTC + hd * 64 + db;
  float4 r0, r1;
  r0.x = acc[0]; r0.y = acc[1]; r0.z = acc[2]; r0.w = acc[3];
  r1.x = acc[4]; r1.y = acc[5]; r1.z = acc[6]; r1.w = acc[7];
  *(float4*)(dst)     = r0;
  *(float4*)(dst + 4) = r1;
}

extern "C" void kernel_launch(void* const* d_in, const int* in_sizes, int n_in,
                              void* d_out, int out_size, void* d_ws, size_t ws_size,
                              hipStream_t stream) {
  (void)in_sizes; (void)n_in; (void)out_size; (void)ws_size;
  const float* x  = (const float*)d_in[0];
  const float* Wq = (const float*)d_in[1];
  const float* bq = (const float*)d_in[2];
  const float* Wk = (const float*)d_in[3];
  const float* bk = (const float*)d_in[4];
  const float* Wv = (const float*)d_in[5];
  const float* bv = (const float*)d_in[6];

  char* ws = (char*)d_ws;
  float*    Lp  = (float*)   (ws);              //   589,824 B
  _Float16* Qh  = (_Float16*)(ws + 1179648);    // 1,179,648 B
  _Float16* KF  = (_Float16*)(ws + 2359296);    // 1,179,648 B (fragment-major)
  _Float16* VF  = (_Float16*)(ws + 3538944);    // 1,179,648 B (fragment-major, smoothed)
  _Float16* Op  = (_Float16*)(ws + 4718592);    // 9,437,184 B (ends 14,155,776)
  float* out = (float*)d_out;

  k_proj   <<<dim3(36, 4, 3), dim3(256), 0, stream>>>(x, Wq, Wk, Wv, bq, bk, bv, Qh, KF, VF);
  k_flash  <<<dim3(18, 16, 4), dim3(256), 0, stream>>>(Qh, KF, VF, Op, Lp);
  k_combine<<<dim3(288), dim3(256), 0, stream>>>(Op, Lp, out);
}

// Round 18
// 68.798 us; speedup vs baseline: 1.0895x; 1.0895x over previous
//
#include <hip/hip_runtime.h>

// SparseSelfAttention, algebraically reduced:
//   out[hd] = sum_g c_g * softmax(Q_hd K_g^T / 16) @ Vs[(2hd-g)%4]
//   Vs[head][j] = sum_{w=-2..2} v[head][(j+2w)%N]
//   c_g = 2 if (hd-g)%4==2 else 1
// N=2304 tokens, 4 heads, dh=64.
//
// R18: SETPRIO REMOVAL (single-variable A/B vs R16). Evidence: R4 (no
// barriers, all-reg, 2304 waves x 18 tiles) and R17 (barriers, K-LDS, 4608
// waves x 9 tiles) have IDENTICAL total body count (41472) and identical
// time (45/42us) -> ~2400 cyc/body with ~1 effective wave/SIMD (occupancy
// 15%), vs ~300 cyc modeled. Waves don't interleave. Since R5/R6 every body
// wraps its MFMA clusters in s_setprio(1) covering most of body duration --
// a prio-1 wave starves co-resident prio-0 waves' load issue (m190: setprio
// HURTS barrier-lockstep kernels; only pays with wave role-diversity).
// All else identical to R16 (3 kernels, no unions, K+V LDS dbuf, counted
// vmcnt + raw barriers).

#define N_TOK 2304
#define OUTC 256
#define HSZ (N_TOK * 64)   // halfs per head = 147456

typedef _Float16 half8 __attribute__((ext_vector_type(8)));
typedef _Float16 half4 __attribute__((ext_vector_type(4)));
typedef float f32x4 __attribute__((ext_vector_type(4)));

typedef __attribute__((address_space(3))) unsigned int as3_u32;
typedef __attribute__((address_space(1))) unsigned int as1_u32;

__device__ __forceinline__ f32x4 mfma16(half8 a, half8 b, f32x4 c) {
  return __builtin_amdgcn_mfma_f32_16x16x32_f16(a, b, c, 0, 0, 0);
}

__device__ __forceinline__ void gload_lds16(const _Float16* g, _Float16* l) {
  __builtin_amdgcn_global_load_lds((const as1_u32*)g, (as3_u32*)l, 16, 0, 0);
}

// by-value f32x8 -> f16x8 convert; compiler fuses cast pairs to v_cvt_pk (m240)
__device__ __forceinline__ half8 cvt8(float4 a, float4 b) {
  half8 h;
  h[0] = (_Float16)a.x; h[1] = (_Float16)a.y; h[2] = (_Float16)a.z; h[3] = (_Float16)a.w;
  h[4] = (_Float16)b.x; h[5] = (_Float16)b.y; h[6] = (_Float16)b.z; h[7] = (_Float16)b.w;
  return h;
}

// ---- kernel 1: QKV projection (f32 in, LDS-staged coalesced epilogues) ----
// mat 0 -> Qh[hd][n][d] row-major, scaled log2(e)/16
// mat 1 -> KF fragment-major: block (bx,hd) owns KF[hd*HSZ + bx*4096 ..+4096)
// mat 2 -> VF fragment-major SMOOTHED: A-operand is xs (5-shift sum of x),
//          bias 5*bv; block (bx,vh) owns VF[vh*HSZ + bx*4096 ..+4096)
__global__ __launch_bounds__(256) void k_proj(
    const float* __restrict__ x, const float* __restrict__ Wq,
    const float* __restrict__ Wk, const float* __restrict__ Wv,
    const float* __restrict__ bq, const float* __restrict__ bk,
    const float* __restrict__ bv,
    _Float16* __restrict__ Qh, _Float16* __restrict__ KF, _Float16* __restrict__ VF) {
  __shared__ _Float16 stg[4096];
  const int w = threadIdx.x >> 6, lane = threadIdx.x & 63;
  const int lr = lane & 15, lk = lane >> 4;
  const int n0 = blockIdx.x * 64 + w * 16;
  const int o0 = blockIdx.y * 64;
  const int mat = blockIdx.z;
  const float* W = (mat == 0) ? Wq : (mat == 1) ? Wk : Wv;
  f32x4 acc[4] = {};

  if (mat == 2) {
    const float* rp0; const float* rp1; const float* rp2;
    const float* rp3; const float* rp4;
    {
      int r0 = (n0 + lr - 4 + N_TOK) % N_TOK;
      int r1 = (n0 + lr - 2 + N_TOK) % N_TOK;
      int r2 = (n0 + lr) % N_TOK;
      int r3 = (n0 + lr + 2) % N_TOK;
      int r4 = (n0 + lr + 4) % N_TOK;
      rp0 = x + (size_t)r0 * OUTC + 8 * lk;
      rp1 = x + (size_t)r1 * OUTC + 8 * lk;
      rp2 = x + (size_t)r2 * OUTC + 8 * lk;
      rp3 = x + (size_t)r3 * OUTC + 8 * lk;
      rp4 = x + (size_t)r4 * OUTC + 8 * lk;
    }
#pragma unroll
    for (int kk = 0; kk < 8; ++kk) {
      float4 s0 = *(const float4*)(rp0 + 32 * kk);
      float4 s1 = *(const float4*)(rp1 + 32 * kk);
      float4 s2 = *(const float4*)(rp2 + 32 * kk);
      float4 s3 = *(const float4*)(rp3 + 32 * kk);
      float4 s4 = *(const float4*)(rp4 + 32 * kk);
      float4 t0 = *(const float4*)(rp0 + 32 * kk + 4);
      float4 t1 = *(const float4*)(rp1 + 32 * kk + 4);
      float4 t2 = *(const float4*)(rp2 + 32 * kk + 4);
      float4 t3 = *(const float4*)(rp3 + 32 * kk + 4);
      float4 t4 = *(const float4*)(rp4 + 32 * kk + 4);
      float4 lo, hi;
      lo.x = s0.x + s1.x + s2.x + s3.x + s4.x;
      lo.y = s0.y + s1.y + s2.y + s3.y + s4.y;
      lo.z = s0.z + s1.z + s2.z + s3.z + s4.z;
      lo.w = s0.w + s1.w + s2.w + s3.w + s4.w;
      hi.x = t0.x + t1.x + t2.x + t3.x + t4.x;
      hi.y = t0.y + t1.y + t2.y + t3.y + t4.y;
      hi.z = t0.z + t1.z + t2.z + t3.z + t4.z;
      hi.w = t0.w + t1.w + t2.w + t3.w + t4.w;
      half8 a = cvt8(lo, hi);
#pragma unroll
      for (int c = 0; c < 4; ++c) {
        const float* wrow = W + (size_t)(o0 + 16*c + lr) * OUTC + 32*kk + 8*lk;
        half8 b = cvt8(*(const float4*)(wrow), *(const float4*)(wrow + 4));
        acc[c] = mfma16(a, b, acc[c]);
      }
    }
    // stage fragment-major + k-slot-permuted:
    //   f = c*128 + (w>>1)*64 + lk*16 + lr,  i = 4*(w&1) + r
#pragma unroll
    for (int c = 0; c < 4; ++c) {
      float bo = 5.0f * bv[o0 + 16*c + lr];
#pragma unroll
      for (int r = 0; r < 4; ++r)
        stg[(c*128 + (w>>1)*64 + lk*16 + lr)*8 + 4*(w&1) + r] =
            (_Float16)(acc[c][r] + bo);
    }
    __syncthreads();
    _Float16* dst = VF + (size_t)blockIdx.y * HSZ + (size_t)blockIdx.x * 4096;
    ((half8*)dst)[threadIdx.x]       = ((const half8*)stg)[threadIdx.x];
    ((half8*)dst)[256 + threadIdx.x] = ((const half8*)stg)[256 + threadIdx.x];
    return;
  }

  const float* xrow = x + (size_t)(n0 + lr) * OUTC + 8 * lk;
#pragma unroll
  for (int kk = 0; kk < 8; ++kk) {
    half8 a = cvt8(*(const float4*)(xrow + 32 * kk),
                   *(const float4*)(xrow + 32 * kk + 4));
#pragma unroll
    for (int c = 0; c < 4; ++c) {
      const float* wrow = W + (size_t)(o0 + 16*c + lr) * OUTC + 32*kk + 8*lk;
      half8 b = cvt8(*(const float4*)(wrow), *(const float4*)(wrow + 4));
      acc[c] = mfma16(a, b, acc[c]);
    }
  }
  const float* bias = (mat == 0) ? bq : bk;
  const int hd = blockIdx.y;

  if (mat == 0) {
    const float qs = 0.0625f * 1.4426950408889634f;   // (1/16) * log2(e)
#pragma unroll
    for (int c = 0; c < 4; ++c) {
      float bo = bias[o0 + 16*c + lr];
      int d = 16*c + lr;
#pragma unroll
      for (int r = 0; r < 4; ++r)
        stg[(w*16 + 4*lk + r) * 64 + d] = (_Float16)((acc[c][r] + bo) * qs);
    }
    __syncthreads();
    _Float16* dst = Qh + ((size_t)hd * N_TOK + blockIdx.x * 64) * 64;
    ((half8*)dst)[threadIdx.x]       = ((const half8*)stg)[threadIdx.x];
    ((half8*)dst)[256 + threadIdx.x] = ((const half8*)stg)[256 + threadIdx.x];
  } else {
    // KF local idx = (w*2+h)*512 + (g4K*16 + 4*lk + r)*8 + iiK  (cK == w)
#pragma unroll
    for (int c = 0; c < 4; ++c) {
      float bo = bias[o0 + 16*c + lr];
      int d = 16*c + lr;
      int h = d >> 5, g4K = (d >> 3) & 3, iiK = d & 7;
#pragma unroll
      for (int r = 0; r < 4; ++r)
        stg[(w*2 + h)*512 + (g4K*16 + 4*lk + r)*8 + iiK] = (_Float16)(acc[c][r] + bo);
    }
    __syncthreads();
    _Float16* dst = KF + (size_t)hd * HSZ + (size_t)blockIdx.x * 4096;
    ((half8*)dst)[threadIdx.x]       = ((const half8*)stg)[threadIdx.x];
    ((half8*)dst)[256 + threadIdx.x] = ((const half8*)stg)[256 + threadIdx.x];
  }
}

// ---- kernel 2: flash attention, LDS tiles, counted vmcnt, NO setprio ----
__global__ __launch_bounds__(256) void k_flash(
    const _Float16* __restrict__ Qh, const _Float16* __restrict__ KF,
    const _Float16* __restrict__ VF,
    _Float16* __restrict__ Opart, float* __restrict__ Lpart) {
  __shared__ __align__(16) _Float16 lds[2][8192];   // [buf][ K:0..4095 | V:4096..8191 ]
  const int wv = threadIdx.x >> 6, lane = threadIdx.x & 63;
  const int lr = lane & 15, g4 = lane >> 4;
  const int strip = blockIdx.x * 4 + wv;      // 0..71, 32 queries each
  const int n0 = strip * 32;
  const int pair = blockIdx.y;                // hd*4 + gk
  const int hd = pair >> 2, gk = pair & 3;
  const int chunk = blockIdx.z;               // 9 tiles each
  const int vh = (2*hd + 4 - gk) & 3;

  const _Float16* Qp = Qh + ((size_t)hd * N_TOK + n0 + lr) * 64 + 8*g4;
  const half8 qa0 = *(const half8*)(Qp);
  const half8 qa1 = *(const half8*)(Qp + 32);
  const half8 qb0 = *(const half8*)(Qp + 16*64);
  const half8 qb1 = *(const half8*)(Qp + 16*64 + 32);

  const _Float16* Kt = KF + (size_t)gk * HSZ + (size_t)chunk * 9 * 4096;
  const _Float16* Vt = VF + (size_t)vh * HSZ + (size_t)chunk * 9 * 4096;
  const _Float16* gsrc = (wv < 2 ? Kt : Vt) + (wv & 1) * 2048 + lane * 8;
  const int ldsoff = (wv < 2 ? 0 : 4096) + (wv & 1) * 2048;

  f32x4 accA[4] = {}, accB[4] = {};
  f32x4 acclA = {}, acclB = {};
  half8 ones;
#pragma unroll
  for (int i = 0; i < 8; ++i) ones[i] = (_Float16)1.0f;

  auto stage = [&](int t, int b) {
    const _Float16* s = gsrc + (size_t)t * 4096;
    _Float16* d = &lds[b][ldsoff];
    gload_lds16(s,        d);
    gload_lds16(s + 512,  d + 512);
    gload_lds16(s + 1024, d + 1024);
    gload_lds16(s + 1536, d + 1536);
  };
  auto body = [&](int b) {
    const _Float16* ldsK = &lds[b][0]    + lane * 8;
    const _Float16* ldsV = &lds[b][4096] + lane * 8;
    f32x4 sA[4], sB[4];
#pragma unroll
    for (int c = 0; c < 4; ++c) {
      half8 k0 = *(const half8*)(ldsK + c*1024);
      half8 k1 = *(const half8*)(ldsK + c*1024 + 512);
      f32x4 tA = {}; tA = mfma16(k0, qa0, tA); tA = mfma16(k1, qa1, tA); sA[c] = tA;
      f32x4 tB = {}; tB = mfma16(k0, qb0, tB); tB = mfma16(k1, qb1, tB); sB[c] = tB;
    }
    // exp2 + pack: named vectors, constant indices only (no unions/pointers)
    half8 pa0, pa1, pb0, pb1;
#pragma unroll
    for (int c = 0; c < 4; ++c) {
      float eA0 = __builtin_amdgcn_exp2f(sA[c][0]);
      float eA1 = __builtin_amdgcn_exp2f(sA[c][1]);
      float eA2 = __builtin_amdgcn_exp2f(sA[c][2]);
      float eA3 = __builtin_amdgcn_exp2f(sA[c][3]);
      float eB0 = __builtin_amdgcn_exp2f(sB[c][0]);
      float eB1 = __builtin_amdgcn_exp2f(sB[c][1]);
      float eB2 = __builtin_amdgcn_exp2f(sB[c][2]);
      float eB3 = __builtin_amdgcn_exp2f(sB[c][3]);
      if (c == 0) {
        pa0[0]=(_Float16)eA0; pa0[1]=(_Float16)eA1; pa0[2]=(_Float16)eA2; pa0[3]=(_Float16)eA3;
        pb0[0]=(_Float16)eB0; pb0[1]=(_Float16)eB1; pb0[2]=(_Float16)eB2; pb0[3]=(_Float16)eB3;
      } else if (c == 1) {
        pa0[4]=(_Float16)eA0; pa0[5]=(_Float16)eA1; pa0[6]=(_Float16)eA2; pa0[7]=(_Float16)eA3;
        pb0[4]=(_Float16)eB0; pb0[5]=(_Float16)eB1; pb0[6]=(_Float16)eB2; pb0[7]=(_Float16)eB3;
      } else if (c == 2) {
        pa1[0]=(_Float16)eA0; pa1[1]=(_Float16)eA1; pa1[2]=(_Float16)eA2; pa1[3]=(_Float16)eA3;
        pb1[0]=(_Float16)eB0; pb1[1]=(_Float16)eB1; pb1[2]=(_Float16)eB2; pb1[3]=(_Float16)eB3;
      } else {
        pa1[4]=(_Float16)eA0; pa1[5]=(_Float16)eA1; pa1[6]=(_Float16)eA2; pa1[7]=(_Float16)eA3;
        pb1[4]=(_Float16)eB0; pb1[5]=(_Float16)eB1; pb1[6]=(_Float16)eB2; pb1[7]=(_Float16)eB3;
      }
    }
#pragma unroll
    for (int cc = 0; cc < 4; ++cc) {
      half8 v0 = *(const half8*)(ldsV + cc*1024);
      half8 v1 = *(const half8*)(ldsV + cc*1024 + 512);
      accA[cc] = mfma16(v0, pa0, accA[cc]); accA[cc] = mfma16(v1, pa1, accA[cc]);
      accB[cc] = mfma16(v0, pb0, accB[cc]); accB[cc] = mfma16(v1, pb1, accB[cc]);
    }
    acclA = mfma16(ones, pa0, acclA); acclA = mfma16(ones, pa1, acclA);
    acclB = mfma16(ones, pb0, acclB); acclB = mfma16(ones, pb1, acclB);
  };

  stage(0, 0);
#pragma unroll 1
  for (int t = 0; t < 9; ++t) {
    if (t < 8) {
      stage(t + 1, (t + 1) & 1);                       // 4 loads in flight
      asm volatile("s_waitcnt vmcnt(4)" ::: "memory"); // own stage(t) landed
    } else {
      asm volatile("s_waitcnt vmcnt(0)" ::: "memory");
    }
    __builtin_amdgcn_sched_barrier(0);
    __builtin_amdgcn_s_barrier();        // all waves' stage(t) landed
    __builtin_amdgcn_sched_barrier(0);
    body(t & 1);
    if (t < 8) {
      __builtin_amdgcn_sched_barrier(0);
      __builtin_amdgcn_s_barrier();      // all readers of buf done before overwrite
    }
  }

  float invA = 1.0f / acclA[0];
  float invB = 1.0f / acclB[0];
  _Float16* Oa = Opart + (((size_t)chunk * 16 + pair) * N_TOK + n0 + lr) * 64;
  _Float16* Ob = Oa + 16 * 64;
#pragma unroll
  for (int cc = 0; cc < 4; ++cc) {
    half4 ha, hb;
#pragma unroll
    for (int r = 0; r < 4; ++r) {
      ha[r] = (_Float16)(accA[cc][r] * invA);
      hb[r] = (_Float16)(accB[cc][r] * invB);
    }
    *(half4*)(Oa + 16*cc + 4*g4) = ha;
    *(half4*)(Ob + 16*cc + 4*g4) = hb;
  }
  if (g4 == 0) {
    Lpart[((size_t)chunk * 16 + pair) * N_TOK + n0 + lr] = acclA[0];
    Lpart[((size_t)chunk * 16 + pair) * N_TOK + n0 + 16 + lr] = acclB[0];
  }
}

// ---- kernel 3: merge split-K chunks (l-weighted), weight by c_g, sum over gk ----
__global__ __launch_bounds__(256) void k_combine(
    const _Float16* __restrict__ Opart, const float* __restrict__ Lpart,
    float* __restrict__ out) {
  int gid = blockIdx.x * 256 + threadIdx.x;   // 73728 total
  int hd = gid / (N_TOK * 8);
  int rem = gid % (N_TOK * 8);
  int n = rem >> 3, db = (rem & 7) * 8;
  float acc[8] = {};
#pragma unroll
  for (int gk = 0; gk < 4; ++gk) {
    float cg = (((hd - gk) & 3) == 2) ? 2.0f : 1.0f;
    int pair = hd * 4 + gk;
    float la[4], lsum = 0.f;
#pragma unroll
    for (int ch = 0; ch < 4; ++ch) {
      la[ch] = Lpart[((size_t)ch * 16 + pair) * N_TOK + n];
      lsum += la[ch];
    }
    float rs = cg / lsum;
#pragma unroll
    for (int ch = 0; ch < 4; ++ch) {
      half8 v = *(const half8*)(Opart + (((size_t)ch * 16 + pair) * N_TOK + n) * 64 + db);
      float w = la[ch] * rs;
#pragma unroll
      for (int i = 0; i < 8; ++i) acc[i] += w * (float)v[i];
    }
  }
  float* dst = out + (size_t)n * OUTC + hd * 64 + db;
  float4 r0, r1;
  r0.x = acc[0]; r0.y = acc[1]; r0.z = acc[2]; r0.w = acc[3];
  r1.x = acc[4]; r1.y = acc[5]; r1.z = acc[6]; r1.w = acc[7];
  *(float4*)(dst)     = r0;
  *(float4*)(dst + 4) = r1;
}

extern "C" void kernel_launch(void* const* d_in, const int* in_sizes, int n_in,
                              void* d_out, int out_size, void* d_ws, size_t ws_size,
                              hipStream_t stream) {
  (void)in_sizes; (void)n_in; (void)out_size; (void)ws_size;
  const float* x  = (const float*)d_in[0];
  const float* Wq = (const float*)d_in[1];
  const float* bq = (const float*)d_in[2];
  const float* Wk = (const float*)d_in[3];
  const float* bk = (const float*)d_in[4];
  const float* Wv = (const float*)d_in[5];
  const float* bv = (const float*)d_in[6];

  char* ws = (char*)d_ws;
  float*    Lp  = (float*)   (ws);              //   589,824 B
  _Float16* Qh  = (_Float16*)(ws + 1179648);    // 1,179,648 B
  _Float16* KF  = (_Float16*)(ws + 2359296);    // 1,179,648 B (fragment-major)
  _Float16* VF  = (_Float16*)(ws + 3538944);    // 1,179,648 B (fragment-major, smoothed)
  _Float16* Op  = (_Float16*)(ws + 4718592);    // 9,437,184 B (ends 14,155,776)
  float* out = (float*)d_out;

  k_proj   <<<dim3(36, 4, 3), dim3(256), 0, stream>>>(x, Wq, Wk, Wv, bq, bk, bv, Qh, KF, VF);
  k_flash  <<<dim3(18, 16, 4), dim3(256), 0, stream>>>(Qh, KF, VF, Op, Lp);
  k_combine<<<dim3(288), dim3(256), 0, stream>>>(Op, Lp, out);
}